// Round 2
// baseline (332.931 us; speedup 1.0000x reference)
//
#include <hip/hip_runtime.h>

typedef __attribute__((ext_vector_type(8))) short s16x8;
typedef __attribute__((ext_vector_type(4))) float f32x4;
typedef __attribute__((ext_vector_type(4))) int i32x4;

#define HW2 262144  // 512*512
#define NSTATE 12

__device__ __forceinline__ unsigned f2b_bits(float f) {
  unsigned u = __builtin_bit_cast(unsigned, f);
  return (u + 0x7fffu + ((u >> 16) & 1u)) >> 16;  // RNE f32->bf16
}

// ---------------- prep: pack A1 (cw = w1@pw, 96x144 padded to 160) , A2 (w2), cb ----------------
// A1 frag (kf in 0..4, mf in 0..5): lane l, elem e holds cw[16*mf + (l&15)][k] with
//   k = 32*kf + 8*(l>>4) + e ; k -> (shift sh = k>>4, chan s = k&15); zero for sh>=9 or s>=12.
// A2 frag f (0..2): lane l elem e holds w2[(l&15)][16*(2f + (e>>2)) + 4*(l>>4) + (e&3)], zero rows>=12.
__global__ void ca_prep(const float* __restrict__ pw, const float* __restrict__ pb,
                        const float* __restrict__ w1, const float* __restrict__ b1,
                        const float* __restrict__ w2,
                        short* __restrict__ A1, short* __restrict__ A2,
                        float* __restrict__ cb) {
  const int b = blockIdx.x, t = threadIdx.x;
  if (b < 30) {
    const int kf = b / 6, mf = b % 6;
    const int blk = t >> 4;
    const int row = 16 * mf + (t & 15);
    short v[8];
#pragma unroll
    for (int e = 0; e < 8; ++e) {
      const int k = 32 * kf + 8 * blk + e;
      const int sh = k >> 4, s = k & 15;
      float acc = 0.f;
      if (sh < 9 && s < 12) {
        const int ky = sh / 3, kx = sh % 3;
        for (int c = 0; c < 48; ++c)
          acc += w1[row * 48 + c] * pw[((c * 12 + s) * 3 + ky) * 3 + kx];
      }
      v[e] = (short)f2b_bits(acc);
    }
    short* dst = A1 + (b * 64 + t) * 8;
#pragma unroll
    for (int e = 0; e < 8; ++e) dst[e] = v[e];
  } else {
    const int blk = t >> 4, row = t & 15;
    for (int f = 0; f < 3; ++f) {
      short* dst = A2 + (f * 64 + t) * 8;
#pragma unroll
      for (int e = 0; e < 8; ++e) {
        const int k = 16 * (2 * f + (e >> 2)) + 4 * blk + (e & 3);
        const float val = (row < 12) ? w2[row * 96 + k] : 0.f;
        dst[e] = (short)f2b_bits(val);
      }
    }
    for (int j = t; j < 96; j += 64) {
      float a = b1[j];
      for (int c = 0; c < 48; ++c) a += w1[j * 48 + c] * pb[c];
      cb[j] = a;
    }
  }
}

// ---------------- main fused kernel ----------------
// Tile: TY=8 rows x TX=64 cols per block (4 waves). LDS: channel-last bf16 [10][66][16].
#define TY 8
#define TX 64
#define LYS 10
#define LXS 66

__launch_bounds__(256, 2)
__global__ void ca_main(const float* __restrict__ x, const int* __restrict__ mask,
                        const short* __restrict__ wsA1, const short* __restrict__ wsA2,
                        const float* __restrict__ wscb, float* __restrict__ out) {
  __shared__ short lds[LYS * LXS * 16 + 8];  // + 16B zero pad block
  const int ZOFF = LYS * LXS * 16;

  const int tid = threadIdx.x;
  const int b = blockIdx.x;
  const int n = b >> 9;
  const int rem = b & 511;
  const int y0 = (rem >> 3) * TY;
  const int x0 = (rem & 7) * TX;

  const int lane = tid & 63;
  const int blk = lane >> 4;
  const int col = lane & 15;

  // ---- per-thread weight fragments (L2-cached, identical across waves) ----
  s16x8 A1[5][6];
#pragma unroll
  for (int kf = 0; kf < 5; ++kf)
#pragma unroll
    for (int mf = 0; mf < 6; ++mf)
      A1[kf][mf] = *(const s16x8*)(wsA1 + ((kf * 6 + mf) * 64 + lane) * 8);
  s16x8 A2[3];
#pragma unroll
  for (int f = 0; f < 3; ++f) A2[f] = *(const s16x8*)(wsA2 + (f * 64 + lane) * 8);
  f32x4 cbv[6];
#pragma unroll
  for (int mf = 0; mf < 6; ++mf)
    cbv[mf] = *(const f32x4*)(wscb + 16 * mf + 4 * blk);

  if (tid == 0) { *(i32x4*)(lds + ZOFF) = (i32x4){0, 0, 0, 0}; }

  // ---- stage x tile (with circular halo) into LDS as bf16, channel-last ----
  const int base_n = n * NSTATE;
  for (int p = tid; p < LYS * LXS; p += 256) {
    const int ly = p / LXS;
    const int lx = p - ly * LXS;
    const int gy = (y0 - 1 + ly) & 511;
    const int gx = (x0 - 1 + lx) & 511;
    const int gbase = base_n * HW2 + (gy << 9) + gx;
    unsigned bs[12];
#pragma unroll
    for (int s = 0; s < 12; ++s) bs[s] = f2b_bits(x[gbase + s * HW2]);
    i32x4 v0 = {(int)(bs[0] | (bs[1] << 16)), (int)(bs[2] | (bs[3] << 16)),
                (int)(bs[4] | (bs[5] << 16)), (int)(bs[6] | (bs[7] << 16))};
    i32x4 v1 = {(int)(bs[8] | (bs[9] << 16)), (int)(bs[10] | (bs[11] << 16)), 0, 0};
    *(i32x4*)(lds + p * 16) = v0;
    *(i32x4*)(lds + p * 16 + 8) = v1;
  }
  __syncthreads();

  // ---- compute: each wave does 8 groups of 16 consecutive pixels ----
  const int wave = tid >> 6;
#pragma unroll 1
  for (int i = 0; i < 8; ++i) {
    const int gid = wave * 8 + i;
    const int ty = gid >> 2;
    const int tx0 = (gid & 3) << 4;

    // B1 gather: 5 frags, one ds_read_b128 each. Lane l, elem e -> patch k=32kf+8blk+e
    s16x8 b1f[5];
#pragma unroll
    for (int kf = 0; kf < 5; ++kf) {
      const int sh = 2 * kf + (blk >> 1);
      const short* ap;
      if (sh < 9) {
        const int ky = sh / 3, kx = sh - 3 * (sh / 3);
        ap = lds + ((ty + ky) * LXS + (tx0 + col + kx)) * 16 + 8 * (blk & 1);
      } else {
        ap = lds + ZOFF;
      }
      b1f[kf] = *(const s16x8*)ap;
    }

    // GEMM1: h = cw @ patch + cb
    f32x4 hacc[6];
#pragma unroll
    for (int mf = 0; mf < 6; ++mf) hacc[mf] = cbv[mf];
#pragma unroll
    for (int kf = 0; kf < 5; ++kf)
#pragma unroll
      for (int mf = 0; mf < 6; ++mf)
        hacc[mf] = __builtin_amdgcn_mfma_f32_16x16x32_bf16(A1[kf][mf], b1f[kf], hacc[mf], 0, 0, 0);

    // ReLU + pack to bf16 B2 frags directly from accumulators, GEMM2: upd = w2 @ h
    f32x4 upd = {0.f, 0.f, 0.f, 0.f};
#pragma unroll
    for (int f = 0; f < 3; ++f) {
      s16x8 b2f;
#pragma unroll
      for (int e = 0; e < 8; ++e) {
        float v = hacc[2 * f + (e >> 2)][e & 3];
        v = v > 0.f ? v : 0.f;
        b2f[e] = (short)f2b_bits(v);
      }
      upd = __builtin_amdgcn_mfma_f32_16x16x32_bf16(A2[f], b2f, upd, 0, 0, 0);
    }

    // epilogue: D2 row = out state (4*blk + r), col = pixel
    if (blk < 3) {
      const int gy = y0 + ty;
      const int gx = x0 + tx0 + col;
      const int gb = (base_n + 4 * blk) * HW2 + (gy << 9) + gx;
#pragma unroll
      for (int r = 0; r < 4; ++r) {
        const int idx = gb + r * HW2;
        out[idx] = x[idx] + upd[r] * (float)mask[idx];
      }
    }
  }
}

extern "C" void kernel_launch(void* const* d_in, const int* in_sizes, int n_in,
                              void* d_out, int out_size, void* d_ws, size_t ws_size,
                              hipStream_t stream) {
  const float* x  = (const float*)d_in[0];
  const float* pw = (const float*)d_in[1];
  const float* pb = (const float*)d_in[2];
  const float* w1 = (const float*)d_in[3];
  const float* b1 = (const float*)d_in[4];
  const float* w2 = (const float*)d_in[5];
  const int* mask = (const int*)d_in[6];
  float* out = (float*)d_out;

  short* A1 = (short*)d_ws;                         // 30*64*16B = 30720
  short* A2 = (short*)((char*)d_ws + 30720);        // 3*64*16B  = 3072
  float* cb = (float*)((char*)d_ws + 30720 + 3072); // 96*4B

  ca_prep<<<31, 64, 0, stream>>>(pw, pb, w1, b1, w2, A1, A2, cb);
  ca_main<<<4096, 256, 0, stream>>>(x, mask, A1, A2, cb, out);
}

// Round 3
// 321.772 us; speedup vs baseline: 1.0347x; 1.0347x over previous
//
#include <hip/hip_runtime.h>

typedef __attribute__((ext_vector_type(8))) short s16x8;
typedef __attribute__((ext_vector_type(4))) float f32x4;
typedef __attribute__((ext_vector_type(4))) int i32x4;

#define HW2 262144  // 512*512
#define NSTATE 12

__device__ __forceinline__ unsigned f2b_bits(float f) {
  unsigned u = __builtin_bit_cast(unsigned, f);
  return (u + 0x7fffu + ((u >> 16) & 1u)) >> 16;  // RNE f32->bf16
}

// ---------------- prep: pack A1 (cw = w1@pw, 96x144 padded to 160), A2 (w2), cb ----------------
// A1 frag (kf 0..4, mf 0..5): lane l elem e holds cw[16mf + (l&15)][k], k = 32kf + 8(l>>4) + e;
//   k -> (sh = k>>4, s = k&15); zero for sh>=9 or s>=12.
// A2 frag f (0..2): lane l elem e holds w2[(l&15)][16(2f + (e>>2)) + 4(l>>4) + (e&3)], zero rows>=12.
__global__ void ca_prep(const float* __restrict__ pw, const float* __restrict__ pb,
                        const float* __restrict__ w1, const float* __restrict__ b1,
                        const float* __restrict__ w2,
                        short* __restrict__ A1, short* __restrict__ A2,
                        float* __restrict__ cb) {
  const int b = blockIdx.x, t = threadIdx.x;
  if (b < 30) {
    const int kf = b / 6, mf = b % 6;
    const int blk = t >> 4;
    const int row = 16 * mf + (t & 15);
    short v[8];
#pragma unroll
    for (int e = 0; e < 8; ++e) {
      const int k = 32 * kf + 8 * blk + e;
      const int sh = k >> 4, s = k & 15;
      float acc = 0.f;
      if (sh < 9 && s < 12) {
        const int ky = sh / 3, kx = sh % 3;
        for (int c = 0; c < 48; ++c)
          acc += w1[row * 48 + c] * pw[((c * 12 + s) * 3 + ky) * 3 + kx];
      }
      v[e] = (short)f2b_bits(acc);
    }
    short* dst = A1 + (b * 64 + t) * 8;
#pragma unroll
    for (int e = 0; e < 8; ++e) dst[e] = v[e];
  } else {
    const int blk = t >> 4, row = t & 15;
    for (int f = 0; f < 3; ++f) {
      short* dst = A2 + (f * 64 + t) * 8;
#pragma unroll
      for (int e = 0; e < 8; ++e) {
        const int k = 16 * (2 * f + (e >> 2)) + 4 * blk + (e & 3);
        const float val = (row < 12) ? w2[row * 96 + k] : 0.f;
        dst[e] = (short)f2b_bits(val);
      }
    }
    for (int j = t; j < 96; j += 64) {
      float a = b1[j];
      for (int c = 0; c < 48; ++c) a += w1[j * 48 + c] * pb[c];
      cb[j] = a;
    }
  }
}

// ---------------- main fused kernel ----------------
// Tile: TY=8 rows x TX=64 cols per block (4 waves). LDS: channel-last bf16 [10][66][16].
#define TY 8
#define TX 64
#define LYS 10
#define LXS 66

// epilogue address for pixel-group gid: lane owns state `col`, pixels [.. +4) at 4*blk
#define EP_ADDR(gid) ((base_n + col) * HW2 + ((y0 + ((gid) >> 2)) << 9) + x0 + (((gid) & 3) << 4) + 4 * blk)

__launch_bounds__(256, 2)
__global__ void ca_main(const float* __restrict__ x, const int* __restrict__ mask,
                        const short* wsA1,  // NOT restrict: stores via `out` may alias ->
                                            // forbids remat of A1 loads -> frags stay in VGPRs
                        const short* __restrict__ wsA2,
                        const float* __restrict__ wscb, float* out /* NOT restrict */) {
  __shared__ short lds[LYS * LXS * 16 + 8];  // + 16B zero pad block
  const int ZOFF = LYS * LXS * 16;

  const int tid = threadIdx.x;
  const int b = blockIdx.x;
  const int n = b >> 9;
  const int rem = b & 511;
  const int y0 = (rem >> 3) * TY;
  const int x0 = (rem & 7) * TX;

  const int lane = tid & 63;
  const int blk = lane >> 4;
  const int col = lane & 15;

  // ---- per-thread weight fragments ----
  s16x8 A1[5][6];
#pragma unroll
  for (int kf = 0; kf < 5; ++kf)
#pragma unroll
    for (int mf = 0; mf < 6; ++mf)
      A1[kf][mf] = *(const s16x8*)(wsA1 + ((kf * 6 + mf) * 64 + lane) * 8);
  s16x8 A2[3];
#pragma unroll
  for (int f = 0; f < 3; ++f) A2[f] = *(const s16x8*)(wsA2 + (f * 64 + lane) * 8);
  f32x4 cbv[6];
#pragma unroll
  for (int mf = 0; mf < 6; ++mf)
    cbv[mf] = *(const f32x4*)(wscb + 16 * mf + 4 * blk);

  if (tid == 0) { *(i32x4*)(lds + ZOFF) = (i32x4){0, 0, 0, 0}; }

  // ---- stage x tile (with circular halo) into LDS as bf16, channel-last ----
  const int base_n = n * NSTATE;
  for (int p = tid; p < LYS * LXS; p += 256) {
    const int ly = p / LXS;
    const int lx = p - ly * LXS;
    const int gy = (y0 - 1 + ly) & 511;
    const int gx = (x0 - 1 + lx) & 511;
    const int gbase = base_n * HW2 + (gy << 9) + gx;
    unsigned bs[12];
#pragma unroll
    for (int s = 0; s < 12; ++s) bs[s] = f2b_bits(x[gbase + s * HW2]);
    i32x4 v0 = {(int)(bs[0] | (bs[1] << 16)), (int)(bs[2] | (bs[3] << 16)),
                (int)(bs[4] | (bs[5] << 16)), (int)(bs[6] | (bs[7] << 16))};
    i32x4 v1 = {(int)(bs[8] | (bs[9] << 16)), (int)(bs[10] | (bs[11] << 16)), 0, 0};
    *(i32x4*)(lds + p * 16) = v0;
    *(i32x4*)(lds + p * 16 + 8) = v1;
  }
  __syncthreads();

  // ---- compute: each wave does 8 groups of 16 consecutive pixels ----
  const int wave = tid >> 6;

  // epilogue prefetch for group 0 of this wave
  f32x4 cxq = {0.f, 0.f, 0.f, 0.f};
  i32x4 cmq = {0, 0, 0, 0};
  if (col < 12) {
    const int a = EP_ADDR(wave * 8);
    cxq = *(const f32x4*)(x + a);
    cmq = *(const i32x4*)(mask + a);
  }

#pragma unroll 1
  for (int i = 0; i < 8; ++i) {
    const int gid = wave * 8 + i;
    const int ty = gid >> 2;
    const int tx0 = (gid & 3) << 4;

    // B1 gather: 5 frags, one ds_read_b128 each. Lane l elem e -> patch k = 32kf + 8blk + e
    s16x8 b1f[5];
#pragma unroll
    for (int kf = 0; kf < 5; ++kf) {
      const int sh = 2 * kf + (blk >> 1);
      const short* ap;
      if (sh < 9) {
        const int ky = sh / 3, kx = sh - 3 * (sh / 3);
        ap = lds + ((ty + ky) * LXS + (tx0 + col + kx)) * 16 + 8 * (blk & 1);
      } else {
        ap = lds + ZOFF;
      }
      b1f[kf] = *(const s16x8*)ap;
    }

    // prefetch next group's epilogue x/mask (hides under the MFMA block)
    f32x4 nxq = {0.f, 0.f, 0.f, 0.f};
    i32x4 nmq = {0, 0, 0, 0};
    if (col < 12) {
      const int a = EP_ADDR(wave * 8 + ((i + 1) & 7));
      nxq = *(const f32x4*)(x + a);
      nmq = *(const i32x4*)(mask + a);
    }

    // GEMM1: h = cw @ patch + cb   (D1: rows = hidden, cols = pixels)
    f32x4 hacc[6];
#pragma unroll
    for (int mf = 0; mf < 6; ++mf) hacc[mf] = cbv[mf];
#pragma unroll
    for (int kf = 0; kf < 5; ++kf)
#pragma unroll
      for (int mf = 0; mf < 6; ++mf)
        hacc[mf] = __builtin_amdgcn_mfma_f32_16x16x32_bf16(A1[kf][mf], b1f[kf], hacc[mf], 0, 0, 0);

    // ReLU + pack to bf16, GEMM2 with SWAPPED operands: D2 rows = pixels, cols = states
    f32x4 upd = {0.f, 0.f, 0.f, 0.f};
#pragma unroll
    for (int f = 0; f < 3; ++f) {
      s16x8 b2f;
#pragma unroll
      for (int e = 0; e < 8; ++e) {
        float v = hacc[2 * f + (e >> 2)][e & 3];
        v = v > 0.f ? v : 0.f;
        b2f[e] = (short)f2b_bits(v);
      }
      upd = __builtin_amdgcn_mfma_f32_16x16x32_bf16(b2f, A2[f], upd, 0, 0, 0);
    }

    // epilogue: lane owns state `col` (<12), 4 consecutive pixels -> float4 everything
    if (col < 12) {
      const int a = EP_ADDR(gid);
      f32x4 o;
#pragma unroll
      for (int r = 0; r < 4; ++r) o[r] = cxq[r] + upd[r] * (float)cmq[r];
      *(f32x4*)(out + a) = o;
    }
    cxq = nxq;
    cmq = nmq;
  }
}

extern "C" void kernel_launch(void* const* d_in, const int* in_sizes, int n_in,
                              void* d_out, int out_size, void* d_ws, size_t ws_size,
                              hipStream_t stream) {
  const float* x  = (const float*)d_in[0];
  const float* pw = (const float*)d_in[1];
  const float* pb = (const float*)d_in[2];
  const float* w1 = (const float*)d_in[3];
  const float* b1 = (const float*)d_in[4];
  const float* w2 = (const float*)d_in[5];
  const int* mask = (const int*)d_in[6];
  float* out = (float*)d_out;

  short* A1 = (short*)d_ws;                         // 30*64*16B = 30720
  short* A2 = (short*)((char*)d_ws + 30720);        // 3*64*16B  = 3072
  float* cb = (float*)((char*)d_ws + 30720 + 3072); // 96*4B

  ca_prep<<<31, 64, 0, stream>>>(pw, pb, w1, b1, w2, A1, A2, cb);
  ca_main<<<4096, 256, 0, stream>>>(x, mask, A1, A2, cb, out);
}